// Round 8
// baseline (357.003 us; speedup 1.0000x reference)
//
#include <hip/hip_runtime.h>
#include <math.h>

// Problem constants
#define NCASES   16
#define NPTS_BIG 65536
#define F1       512
#define OUT_B    4096

typedef __attribute__((ext_vector_type(8)))  short short8;    // 8 bf16 = 4 VGPR (MFMA A/B frag)
typedef __attribute__((ext_vector_type(4)))  float floatx4;   // 16x16 MFMA C/D frag
typedef __attribute__((ext_vector_type(16))) float floatx16;  // 32x32 MFMA C/D frag
typedef unsigned short ush;

__device__ __forceinline__ float silu_f(float x) {
    return x * __builtin_amdgcn_rcpf(1.0f + __expf(-x));
}

// RNE fp32->bf16 left in bits [31:16]  (used in one-time prep only)
__device__ __forceinline__ unsigned f2bf_hi(float x) {
    unsigned u = __float_as_uint(x);
    return u + 0x7FFFu + ((u >> 16) & 1u);
}
__device__ __forceinline__ ush f2bf(float x) {
    return (ush)(f2bf_hi(x) >> 16);
}
// RTZ pack: two f32 -> two bf16 in one v_perm (truncate mantissa; hot-loop path).
__device__ __forceinline__ unsigned pk2bf_rtz(float lo, float hi) {
    return __builtin_amdgcn_perm(__float_as_uint(hi), __float_as_uint(lo), 0x07060302u);
}

// Monotone float -> uint mapping (handles negatives) for atomicMax argmax.
__device__ __forceinline__ unsigned enc_f(float x) {
    unsigned u = __float_as_uint(x);
    return (u & 0x80000000u) ? ~u : (u | 0x80000000u);
}
__device__ __forceinline__ float dec_f(unsigned e) {
    unsigned u = (e & 0x80000000u) ? (e ^ 0x80000000u) : ~e;
    return __uint_as_float(u);
}

// force value to SGPR
__device__ __forceinline__ float sgpr_f(float x) {
    return __uint_as_float(__builtin_amdgcn_readfirstlane(__float_as_uint(x)));
}

// Pre-swizzle W11/W12 into MFMA B-fragment order (bf16, RNE) + zero argmax buffers.
// W11 (16x16x32 B-frag): B[k = KT*32 + (lane>>4)*8 + j][n = lane&15].
//   BbWs: [w(8)][KT(2)][lane(64)][j(8)]               (16 KB)
// W12 (32x32x16 B-frag): B[k = kt*16 + (lane>>5)*8 + j][n = lane&31].
//   BcWs: [w(8)][ct(2)][kt(8)][lane(64)][j(8)]        (128 KB)
__global__ void k_prep(const float* __restrict__ W11, const float* __restrict__ W12,
                       ush* __restrict__ BbWs, ush* __restrict__ BcWs,
                       unsigned long long* __restrict__ argBufs)
{
    int i = blockIdx.x * 256 + threadIdx.x;   // 65536 threads
    if (i < 16384) argBufs[i] = 0ull;         // argBuf + argBuf2
    {
        int j = i & 7, l = (i >> 3) & 63, t = i >> 9;     // t = w*16 + ct*8 + kt
        int kt = t & 7, ct = (t >> 3) & 1, w = t >> 4;
        int k = kt * 16 + ((l >> 5) & 1) * 8 + j;
        int f = w * 64 + ct * 32 + (l & 31);
        BcWs[i] = f2bf(W12[(size_t)k * 512 + f]);
    }
    if (i < 8192) {
        int j = i & 7, l = (i >> 3) & 63, t = i >> 9;     // t = w*2 + KT
        int KT = t & 1, w = t >> 1;
        int k = KT * 32 + (l >> 4) * 8 + j;
        int f = w * 16 + (l & 15);
        BbWs[i] = f2bf(W11[(size_t)k * 128 + f]);
    }
}

// Fused mlp1 + per-feature argmax of PRE-ACTIVATION (silu monotone for x>=-1.278,
// silu(x)<0 for x<0, per-feature max pre-act > 0 w.o.p. -> argmax silu(z) == argmax z).
// b12 added after the max; silu applied downstream (k_head).
//
// PIPELINE (R1 structure -- best measured): double-buffered h0/h1, one barrier/chunk:
//   [B(ch): h0[p]->h1[p];  A(ch+1): ->h0[p^1];  barrier;  C(ch): h1[p]]
//
// STAGE C (this round): 32x32x16 MFMA -- same MACs in 17% fewer MFMA cycles
// (8.07cy/16384 vs 4.85cy/8192) and half the issue slots; LDS traffic identical
// (16x ds_read_b128/wave-chunk, A-frag shared across both col-tiles via
// two-accumulator K-loop).  Live set audit (R3/R6 spill lessons): Bc 64 + Bb 8
// + acc0/acc1 32 + a 4 + bestv 2 + misc ~ 120 <= 128.
// Argmax: 8-bit code-in-mantissa (ch<<5|rg<<4|reg), strip 0xFF (~3e-5 rel);
// cols = lane&31 -> single shfl_xor(32) at flush.
// LDS 53.2 KB -> 2 blocks/CU.  __launch_bounds__(512,4): pin total regs <= 128.
template<bool GATHER>
__global__ __launch_bounds__(512, 4)
void k_mlp1_argmax(const float* __restrict__ pts, int nPts, int chunksPerBlock,
                   const unsigned long long* __restrict__ gatherIdx,
                   const float* __restrict__ W10, const float* __restrict__ b10,
                   const float* __restrict__ b11, const float* __restrict__ b12,
                   const ush* __restrict__ BbWs,
                   const ush* __restrict__ BcWs,
                   unsigned long long* __restrict__ argOut)
{
    const int c   = blockIdx.y;
    const int tid = threadIdx.x;
    const int w   = tid >> 6;   // wave 0..7
    const int l   = tid & 63;   // lane
    const int lm  = l & 15;     // m/n within 16x16 tile (stages A/B)
    const int q   = l >> 4;     // quad (stages A/B)
    const int ln  = l & 31;     // n/m within 32x32 tile (stage C)
    const int hi  = l >> 5;     // half (stage C)

    __shared__ __align__(16) ush s_h0[2][64][72];   // bf16, stride 144B, dbuf
    __shared__ __align__(16) ush s_h1[2][64][136];  // bf16, stride 272B, dbuf

    const int wf = __builtin_amdgcn_readfirstlane(w);   // wave-uniform

    // stage-A weights in SGPRs (no LDS, no per-chunk reloads)
    float wA0[8], wA1[8], wA2[8], bA[8];
    #pragma unroll
    for (int j = 0; j < 8; ++j) {
        wA0[j] = sgpr_f(W10[  0 + wf * 8 + j]);
        wA1[j] = sgpr_f(W10[ 64 + wf * 8 + j]);
        wA2[j] = sgpr_f(W10[128 + wf * 8 + j]);
        bA[j]  = sgpr_f(b10[       wf * 8 + j]);
    }

    // persistent B fragments (AGPR side of the unified file)
    short8 Bc[16];   // [ct*8+kt] 32x32x16 frags for W12 slice (cols wf*64+ct*32+ln)
    #pragma unroll
    for (int t = 0; t < 16; ++t)
        Bc[t] = *(const short8*)(BcWs + (size_t)((wf * 16 + t) * 64 + l) * 8);
    short8 Bb[2];    // [KT] 16x16x32 frags for W11 slice
    #pragma unroll
    for (int t = 0; t < 2; ++t)
        Bb[t] = *(const short8*)(BbWs + (size_t)((wf * 2 + t) * 64 + l) * 8);

    const float bias11 = b11[wf * 16 + lm];
    const floatx4 bias4 = {bias11, bias11, bias11, bias11};
    const floatx16 zero16 = {0.f,0.f,0.f,0.f, 0.f,0.f,0.f,0.f,
                             0.f,0.f,0.f,0.f, 0.f,0.f,0.f,0.f};

    float bestv[2];
    bestv[0] = -INFINITY; bestv[1] = -INFINITY;

    const float* cpts = pts + (size_t)c * nPts * 3;

    // ---- helpers ----
    auto ldpt = [&](int ch, float& xx, float& yy, float& zz) {
        const int pbase = (blockIdx.x * chunksPerBlock + ch) * 64;
        if (GATHER) {
            unsigned gi = ~(unsigned)(gatherIdx[(size_t)c * 512 + pbase + l] & 0xFFFFFFFFull);
            const float* sp = cpts + (size_t)gi * 3;
            xx = sp[0]; yy = sp[1]; zz = sp[2];
        } else {
            const float* sp = cpts + (size_t)(pbase + l) * 3;
            xx = sp[0]; yy = sp[1]; zz = sp[2];
        }
    };
    // stage A: h0[p][64][64] = silu(pts @ W10 + b10); lane = point, wave = 8 feats
    auto stageA = [&](int p, float xx, float yy, float zz) {
        float v[8];
        #pragma unroll
        for (int j = 0; j < 8; ++j) {
            float t = fmaf(zz, wA2[j], bA[j]);
            t = fmaf(yy, wA1[j], t);
            t = fmaf(xx, wA0[j], t);
            v[j] = silu_f(t);
        }
        uint4 hv = { pk2bf_rtz(v[0], v[1]), pk2bf_rtz(v[2], v[3]),
                     pk2bf_rtz(v[4], v[5]), pk2bf_rtz(v[6], v[7]) };
        *(uint4*)&s_h0[p][l][wf * 8] = hv;   // 16B aligned
    };

    // ---- prologue: A(0) ----
    {
        float xx, yy, zz;
        ldpt(0, xx, yy, zz);
        stageA(0, xx, yy, zz);
    }
    __syncthreads();

    for (int ch = 0; ch < chunksPerBlock; ++ch) {
        const int p = ch & 1;
        const bool more = (ch + 1 < chunksPerBlock);

        // issue next chunk's point loads early (hide under stage-B MFMAs)
        float nx, ny, nz;
        if (more) ldpt(ch + 1, nx, ny, nz);

        // ---- stage B: h1[p][64][128] = silu(h0[p] @ W11 + b11); bias as MFMA C-init ----
        #pragma unroll
        for (int MT = 0; MT < 4; ++MT) {
            short8 a0 = *(const short8*)&s_h0[p][MT * 16 + lm][q * 8];        // A[m=lm][k=q*8+j]
            short8 a1 = *(const short8*)&s_h0[p][MT * 16 + lm][32 + q * 8];
            floatx4 acc = __builtin_amdgcn_mfma_f32_16x16x32_bf16(a0, Bb[0], bias4, 0, 0, 0);
            acc = __builtin_amdgcn_mfma_f32_16x16x32_bf16(a1, Bb[1], acc, 0, 0, 0);
            #pragma unroll
            for (int r = 0; r < 4; ++r) {  // C/D: row = q*4+r (point), col = lm (feature)
                unsigned uv = __float_as_uint(silu_f(acc[r]));   // RTZ bf16: raw hi-half
                s_h1[p][MT * 16 + q * 4 + r][wf * 16 + lm] = (ush)(uv >> 16);
            }
        }

        // ---- stage A for chunk ch+1 into the other h0 buffer ----
        if (more) stageA(p ^ 1, nx, ny, nz);

        __syncthreads();   // h1[p] ready for C(ch); h0[p^1] ready for B(ch+1)

        // ---- stage C: pre-act feats = h1[p] @ W12 via 32x32x16; 8-bit code argmax ----
        // A-frag: lane(ln,hi), elem j -> A[m=ln][k = kt*16 + hi*8 + j] = h1[rg*32+ln][...]
        // D: lane(ln,hi), reg r -> row (r&3)+8*(r>>2)+4*hi, col ln.
        const int cbC = 255 - (ch << 5);
        #pragma unroll
        for (int rg = 0; rg < 2; ++rg) {
            floatx16 acc0 = zero16, acc1 = zero16;
            #pragma unroll
            for (int kt = 0; kt < 8; ++kt) {
                short8 a = *(const short8*)&s_h1[p][rg * 32 + ln][kt * 16 + hi * 8];
                acc0 = __builtin_amdgcn_mfma_f32_32x32x16_bf16(a, Bc[kt],     acc0, 0, 0, 0);
                acc1 = __builtin_amdgcn_mfma_f32_32x32x16_bf16(a, Bc[8 + kt], acc1, 0, 0, 0);
            }
            const int cb = cbC - (rg << 4);
            #pragma unroll
            for (int r = 0; r < 16; r += 4) {   // ct=0 tile -> bestv[0]
                float x0 = __uint_as_float((__float_as_uint(acc0[r    ]) & 0xFFFFFF00u) | (unsigned)(cb - r));
                float x1 = __uint_as_float((__float_as_uint(acc0[r + 1]) & 0xFFFFFF00u) | (unsigned)(cb - r - 1));
                float x2 = __uint_as_float((__float_as_uint(acc0[r + 2]) & 0xFFFFFF00u) | (unsigned)(cb - r - 2));
                float x3 = __uint_as_float((__float_as_uint(acc0[r + 3]) & 0xFFFFFF00u) | (unsigned)(cb - r - 3));
                float t0 = fmaxf(fmaxf(x0, x1), x2);
                bestv[0] = fmaxf(fmaxf(t0, x3), bestv[0]);
            }
            #pragma unroll
            for (int r = 0; r < 16; r += 4) {   // ct=1 tile -> bestv[1]
                float x0 = __uint_as_float((__float_as_uint(acc1[r    ]) & 0xFFFFFF00u) | (unsigned)(cb - r));
                float x1 = __uint_as_float((__float_as_uint(acc1[r + 1]) & 0xFFFFFF00u) | (unsigned)(cb - r - 1));
                float x2 = __uint_as_float((__float_as_uint(acc1[r + 2]) & 0xFFFFFF00u) | (unsigned)(cb - r - 2));
                float x3 = __uint_as_float((__float_as_uint(acc1[r + 3]) & 0xFFFFFF00u) | (unsigned)(cb - r - 3));
                float t0 = fmaxf(fmaxf(x0, x1), x2);
                bestv[1] = fmaxf(fmaxf(t0, x3), bestv[1]);
            }
        }
    }

    // ---- flush: decode 8-bit code, strip it, combine lane-halves, add b12, atomicMax ----
    #pragma unroll
    for (int ct = 0; ct < 2; ++ct) {
        unsigned u = __float_as_uint(bestv[ct]);
        int t = 255 - (int)(u & 255u);            // = ch<<5 | rg<<4 | reg  (exact)
        int reg = t & 15, rg = (t >> 4) & 1, ch = t >> 5;
        int row = (reg & 3) + 8 * (reg >> 2) + 4 * hi;
        unsigned idx = (unsigned)((blockIdx.x * chunksPerBlock + ch) * 64 + rg * 32 + row);
        float v = __uint_as_float(u & 0xFFFFFF00u) + b12[wf * 64 + ct * 32 + ln];
        float    vo = __shfl_xor(v, 32, 64);
        unsigned io = __shfl_xor(idx, 32, 64);
        if (vo > v || (vo == v && io < idx)) { v = vo; idx = io; }
        if (hi == 0) {
            unsigned long long key = ((unsigned long long)enc_f(v) << 32)
                                   | (unsigned long long)(~idx);
            atomicMax(&argOut[(size_t)c * 512 + wf * 64 + ct * 32 + ln], key);
        }
    }
}

// Head: latent0 = silu(decoded max pre-act) -> silu(@W20+b20) -> @W21+b21. One block/case.
__global__ __launch_bounds__(256)
void k_head(const unsigned long long* __restrict__ argBuf2,
            const float* __restrict__ W20, const float* __restrict__ b20,
            const float* __restrict__ W21, const float* __restrict__ b21,
            float* __restrict__ latent)
{
    const int c = blockIdx.x, tid = threadIdx.x;
    __shared__ float l0[512];
    __shared__ float hh[256];
    l0[tid]       = silu_f(dec_f((unsigned)(argBuf2[(size_t)c * 512 + tid] >> 32)));
    l0[tid + 256] = silu_f(dec_f((unsigned)(argBuf2[(size_t)c * 512 + tid + 256] >> 32)));
    __syncthreads();
    float acc = b20[tid];
    for (int k = 0; k < 512; ++k) acc += l0[k] * W20[(size_t)k * 256 + tid];
    hh[tid] = silu_f(acc);
    __syncthreads();
    #pragma unroll
    for (int r = 0; r < 2; ++r) {
        int f = tid + r * 256;
        float a2 = b21[f];
        for (int k = 0; k < 256; ++k) a2 += hh[k] * W21[(size_t)k * 512 + f];
        latent[(size_t)c * 512 + f] = a2;
    }
}

// out[b][:] = latent[x[b]][:]
__global__ void k_scatter(const int* __restrict__ x,
                          const float* __restrict__ latent,
                          float* __restrict__ out)
{
    const int b = blockIdx.x, t = threadIdx.x;   // 128 threads, float4 each
    int cid = x[b];
    const float4* src = (const float4*)(latent + (size_t)cid * 512);
    float4* dst = (float4*)(out + (size_t)b * 512);
    dst[t] = src[t];
}

extern "C" void kernel_launch(void* const* d_in, const int* in_sizes, int n_in,
                              void* d_out, int out_size, void* d_ws, size_t ws_size,
                              hipStream_t stream)
{
    const float* pts = (const float*)d_in[0];
    const float* W10 = (const float*)d_in[1];
    const float* b10 = (const float*)d_in[2];
    const float* W11 = (const float*)d_in[3];
    const float* b11 = (const float*)d_in[4];
    const float* W12 = (const float*)d_in[5];
    const float* b12 = (const float*)d_in[6];
    const float* W20 = (const float*)d_in[7];
    const float* b20 = (const float*)d_in[8];
    const float* W21 = (const float*)d_in[9];
    const float* b21 = (const float*)d_in[10];
    const int*   x   = (const int*)d_in[11];
    float* out = (float*)d_out;

    // Workspace layout (re-poisoned every call -> rebuild every call):
    char* ws = (char*)d_ws;
    unsigned long long* argBuf  = (unsigned long long*)ws;              //  64 KB
    unsigned long long* argBuf2 = (unsigned long long*)(ws + 65536);    //  64 KB
    float* latent               = (float*)(ws + 131072);                //  32 KB
    ush* BbWs                   = (ush*)(ws + 163840);                  //  16 KB
    ush* BcWs                   = (ush*)(ws + 180224);                  // 128 KB (total 308 KB)

    // prep: swizzle weights to MFMA B-frag order + zero both argmax buffers
    k_prep<<<dim3(256), dim3(256), 0, stream>>>(W11, W12, BbWs, BcWs, argBuf);

    // Phase 1: big MLP + argmax over 65536 points/case
    k_mlp1_argmax<false><<<dim3(128, NCASES), dim3(512), 0, stream>>>(
        pts, NPTS_BIG, 8, nullptr, W10, b10, b11, b12, BbWs, BcWs, argBuf);

    // Phase 2+3 fused: MLP over 512 critical points/case (gather via argBuf) + max
    k_mlp1_argmax<true><<<dim3(8, NCASES), dim3(512), 0, stream>>>(
        pts, NPTS_BIG, 1, argBuf, W10, b10, b11, b12, BbWs, BcWs, argBuf2);

    // Phase 4: head MLP per case (applies silu to decoded max)
    k_head<<<dim3(NCASES), dim3(256), 0, stream>>>(argBuf2, W20, b20, W21, b21, latent);

    // Phase 5: scatter latent rows to output by case id
    k_scatter<<<dim3(OUT_B), dim3(128), 0, stream>>>(x, latent, out);
}

// Round 9
// 281.673 us; speedup vs baseline: 1.2674x; 1.2674x over previous
//
#include <hip/hip_runtime.h>
#include <math.h>

// Problem constants
#define NCASES   16
#define NPTS_BIG 65536
#define F1       512
#define OUT_B    4096

typedef __attribute__((ext_vector_type(8))) short  short8;   // 8 bf16 = 4 VGPR (MFMA A/B frag)
typedef __attribute__((ext_vector_type(4))) float  floatx4;  // MFMA C/D frag
typedef unsigned short ush;

__device__ __forceinline__ float silu_f(float x) {
    return x * __builtin_amdgcn_rcpf(1.0f + __expf(-x));
}

// RNE fp32->bf16 left in bits [31:16]  (used in one-time prep only)
__device__ __forceinline__ unsigned f2bf_hi(float x) {
    unsigned u = __float_as_uint(x);
    return u + 0x7FFFu + ((u >> 16) & 1u);
}
__device__ __forceinline__ ush f2bf(float x) {
    return (ush)(f2bf_hi(x) >> 16);
}
// RTZ pack: two f32 -> two bf16 in one v_perm (truncate mantissa; hot-loop path).
__device__ __forceinline__ unsigned pk2bf_rtz(float lo, float hi) {
    return __builtin_amdgcn_perm(__float_as_uint(hi), __float_as_uint(lo), 0x07060302u);
}

// Monotone float -> uint mapping (handles negatives) for atomicMax argmax.
__device__ __forceinline__ unsigned enc_f(float x) {
    unsigned u = __float_as_uint(x);
    return (u & 0x80000000u) ? ~u : (u | 0x80000000u);
}
__device__ __forceinline__ float dec_f(unsigned e) {
    unsigned u = (e & 0x80000000u) ? (e ^ 0x80000000u) : ~e;
    return __uint_as_float(u);
}

// force value to SGPR
__device__ __forceinline__ float sgpr_f(float x) {
    return __uint_as_float(__builtin_amdgcn_readfirstlane(__float_as_uint(x)));
}

// Pre-swizzle W11/W12 into MFMA B-fragment order (bf16, RNE) + zero argmax buffers.
// B-layout for 16x16x32: B[k = KT*32 + (lane>>4)*8 + j][n = lane&15].
// BcWs: [w(8)][NT(4)][KT(4)][lane(64)][j(8)]  (W12, 128 KB)
// BbWs: [w(8)][KT(2)][lane(64)][j(8)]         (W11, 16 KB)
__global__ void k_prep(const float* __restrict__ W11, const float* __restrict__ W12,
                       ush* __restrict__ BbWs, ush* __restrict__ BcWs,
                       unsigned long long* __restrict__ argBufs)
{
    int i = blockIdx.x * 256 + threadIdx.x;   // 65536 threads
    if (i < 16384) argBufs[i] = 0ull;         // argBuf + argBuf2
    {
        int j = i & 7, l = (i >> 3) & 63, t = i >> 9;     // t = w*16 + NT*4 + KT
        int KT = t & 3, NT = (t >> 2) & 3, w = t >> 4;
        int k = KT * 32 + (l >> 4) * 8 + j;
        int f = w * 64 + NT * 16 + (l & 15);
        BcWs[i] = f2bf(W12[(size_t)k * 512 + f]);
    }
    if (i < 8192) {
        int j = i & 7, l = (i >> 3) & 63, t = i >> 9;     // t = w*2 + KT
        int KT = t & 1, w = t >> 1;
        int k = KT * 32 + (l >> 4) * 8 + j;
        int f = w * 16 + (l & 15);
        BbWs[i] = f2bf(W11[(size_t)k * 128 + f]);
    }
}

// Fused mlp1 + per-feature argmax of PRE-ACTIVATION (silu monotone for x>=-1.278,
// silu(x)<0 for x<0, per-feature max pre-act > 0 w.o.p. -> argmax silu(z) == argmax z).
// b12 added after the max; silu applied downstream (k_head).
//
// CONVERGED CONFIGURATION (R1 structure; protect it):
// double-buffered h0/h1, ONE barrier per chunk:
//   [B(ch): h0[p]->h1[p];  A(ch+1): ->h0[p^1];  barrier;  C(ch): h1[p]]
// Settled findings (R0-R8): barrier halving neutral (R1); h1 bank swizzle
// neutral -- SQ_LDS_BANK_CONFLICT is inherent b128 access-splitting (R2);
// C||B||A jam neutral, full-unroll jam spills Bc (R3/R4); 6-wave occupancy
// spills (R6); 32x32x16 stage C spills (R8).  The live set (Bc 64 + Bb 8 +
// working regs ~ 120 of 128) has NO headroom: any variant adding >=16 live
// registers spills and loses 1.5x.  Phase-1 is latency-bound at 4 waves/SIMD,
// pipes MFMA ~45% / LDS ~43% / VALU ~27%, wall 164-167us across 6 variants.
// LDS 53.2 KB -> 2 blocks/CU.  __launch_bounds__(512,4): pin total regs <= 128.
template<bool GATHER>
__global__ __launch_bounds__(512, 4)
void k_mlp1_argmax(const float* __restrict__ pts, int nPts, int chunksPerBlock,
                   const unsigned long long* __restrict__ gatherIdx,
                   const float* __restrict__ W10, const float* __restrict__ b10,
                   const float* __restrict__ b11, const float* __restrict__ b12,
                   const ush* __restrict__ BbWs,
                   const ush* __restrict__ BcWs,
                   unsigned long long* __restrict__ argOut)
{
    const int c   = blockIdx.y;
    const int tid = threadIdx.x;
    const int w   = tid >> 6;   // wave 0..7
    const int l   = tid & 63;   // lane
    const int lm  = l & 15;     // m/n within 16x16 tile
    const int q   = l >> 4;     // quad

    __shared__ __align__(16) ush s_h0[2][64][72];   // bf16, stride 144B, dbuf
    __shared__ __align__(16) ush s_h1[2][64][136];  // bf16, stride 272B, dbuf

    const int wf = __builtin_amdgcn_readfirstlane(w);   // wave-uniform

    // stage-A weights in SGPRs (no LDS, no per-chunk reloads)
    float wA0[8], wA1[8], wA2[8], bA[8];
    #pragma unroll
    for (int j = 0; j < 8; ++j) {
        wA0[j] = sgpr_f(W10[  0 + wf * 8 + j]);
        wA1[j] = sgpr_f(W10[ 64 + wf * 8 + j]);
        wA2[j] = sgpr_f(W10[128 + wf * 8 + j]);
        bA[j]  = sgpr_f(b10[       wf * 8 + j]);
    }

    // persistent B fragments (AGPR side of the unified file)
    short8 Bc[16];   // [NT*4+KT] for W12 slice
    #pragma unroll
    for (int t = 0; t < 16; ++t)
        Bc[t] = *(const short8*)(BcWs + (size_t)((wf * 16 + t) * 64 + l) * 8);
    short8 Bb[2];    // [KT] for W11 slice
    #pragma unroll
    for (int t = 0; t < 2; ++t)
        Bb[t] = *(const short8*)(BbWs + (size_t)((wf * 2 + t) * 64 + l) * 8);

    const float bias11 = b11[wf * 16 + lm];
    const floatx4 bias4 = {bias11, bias11, bias11, bias11};
    const floatx4 zero4 = {0.f, 0.f, 0.f, 0.f};

    float bestv[4];
    #pragma unroll
    for (int NT = 0; NT < 4; ++NT) bestv[NT] = -INFINITY;

    const float* cpts = pts + (size_t)c * nPts * 3;

    // ---- helpers ----
    auto ldpt = [&](int ch, float& xx, float& yy, float& zz) {
        const int pbase = (blockIdx.x * chunksPerBlock + ch) * 64;
        if (GATHER) {
            unsigned gi = ~(unsigned)(gatherIdx[(size_t)c * 512 + pbase + l] & 0xFFFFFFFFull);
            const float* sp = cpts + (size_t)gi * 3;
            xx = sp[0]; yy = sp[1]; zz = sp[2];
        } else {
            const float* sp = cpts + (size_t)(pbase + l) * 3;
            xx = sp[0]; yy = sp[1]; zz = sp[2];
        }
    };
    // stage A: h0[p][64][64] = silu(pts @ W10 + b10); lane = point, wave = 8 feats
    auto stageA = [&](int p, float xx, float yy, float zz) {
        float v[8];
        #pragma unroll
        for (int j = 0; j < 8; ++j) {
            float t = fmaf(zz, wA2[j], bA[j]);
            t = fmaf(yy, wA1[j], t);
            t = fmaf(xx, wA0[j], t);
            v[j] = silu_f(t);
        }
        uint4 hv = { pk2bf_rtz(v[0], v[1]), pk2bf_rtz(v[2], v[3]),
                     pk2bf_rtz(v[4], v[5]), pk2bf_rtz(v[6], v[7]) };
        *(uint4*)&s_h0[p][l][wf * 8] = hv;   // 16B aligned
    };

    // ---- prologue: A(0) ----
    {
        float xx, yy, zz;
        ldpt(0, xx, yy, zz);
        stageA(0, xx, yy, zz);
    }
    __syncthreads();

    for (int ch = 0; ch < chunksPerBlock; ++ch) {
        const int p = ch & 1;
        const bool more = (ch + 1 < chunksPerBlock);

        // issue next chunk's point loads early (hide under stage-B MFMAs)
        float nx, ny, nz;
        if (more) ldpt(ch + 1, nx, ny, nz);

        // ---- stage B: h1[p][64][128] = silu(h0[p] @ W11 + b11); bias as MFMA C-init ----
        #pragma unroll
        for (int MT = 0; MT < 4; ++MT) {
            short8 a0 = *(const short8*)&s_h0[p][MT * 16 + lm][q * 8];        // A[m=lm][k=q*8+j]
            short8 a1 = *(const short8*)&s_h0[p][MT * 16 + lm][32 + q * 8];
            floatx4 acc = __builtin_amdgcn_mfma_f32_16x16x32_bf16(a0, Bb[0], bias4, 0, 0, 0);
            acc = __builtin_amdgcn_mfma_f32_16x16x32_bf16(a1, Bb[1], acc, 0, 0, 0);
            #pragma unroll
            for (int r = 0; r < 4; ++r) {  // C/D: row = q*4+r (point), col = lm (feature)
                unsigned uv = __float_as_uint(silu_f(acc[r]));   // RTZ bf16: raw hi-half
                s_h1[p][MT * 16 + q * 4 + r][wf * 16 + lm] = (ush)(uv >> 16);
            }
        }

        // ---- stage A for chunk ch+1 into the other h0 buffer ----
        if (more) stageA(p ^ 1, nx, ny, nz);

        __syncthreads();   // h1[p] ready for C(ch); h0[p^1] ready for B(ch+1)

        // ---- stage C: pre-act feats = h1[p] @ W12; code-in-mantissa max3 argmax ----
        const int cb0 = 127 - (ch << 4);
        #pragma unroll
        for (int MT = 0; MT < 4; ++MT) {
            short8 a[4];
            #pragma unroll
            for (int KT = 0; KT < 4; ++KT)
                a[KT] = *(const short8*)&s_h1[p][MT * 16 + lm][KT * 32 + q * 8];
            const int cbM = cb0 - (MT << 2);
            #pragma unroll
            for (int NT = 0; NT < 4; ++NT) {
                floatx4 acc = __builtin_amdgcn_mfma_f32_16x16x32_bf16(a[0], Bc[NT * 4 + 0], zero4, 0, 0, 0);
                #pragma unroll
                for (int KT = 1; KT < 4; ++KT)
                    acc = __builtin_amdgcn_mfma_f32_16x16x32_bf16(a[KT], Bc[NT * 4 + KT], acc, 0, 0, 0);
                float x0 = __uint_as_float((__float_as_uint(acc[0]) & 0xFFFFFF80u) | (unsigned)(cbM));
                float x1 = __uint_as_float((__float_as_uint(acc[1]) & 0xFFFFFF80u) | (unsigned)(cbM - 1));
                float x2 = __uint_as_float((__float_as_uint(acc[2]) & 0xFFFFFF80u) | (unsigned)(cbM - 2));
                float x3 = __uint_as_float((__float_as_uint(acc[3]) & 0xFFFFFF80u) | (unsigned)(cbM - 3));
                float t0 = fmaxf(fmaxf(x0, x1), x2);
                bestv[NT] = fmaxf(fmaxf(t0, x3), bestv[NT]);
            }
        }
    }

    // ---- flush: decode code, strip it, combine quads via shfl, add b12, atomicMax ----
    #pragma unroll
    for (int NT = 0; NT < 4; ++NT) {
        unsigned u = __float_as_uint(bestv[NT]);
        int t = 127 - (int)(u & 127u);            // = ch<<4 | MT<<2 | r  (exact)
        unsigned idx = (unsigned)((blockIdx.x * chunksPerBlock + (t >> 4)) * 64
                                  + ((t >> 2) & 3) * 16 + q * 4 + (t & 3));
        float v = __uint_as_float(u & 0xFFFFFF80u) + b12[wf * 64 + NT * 16 + lm];
        #pragma unroll
        for (int m = 16; m <= 32; m <<= 1) {
            float    vo = __shfl_xor(v, m, 64);
            unsigned io = __shfl_xor(idx, m, 64);
            if (vo > v || (vo == v && io < idx)) { v = vo; idx = io; }
        }
        if (q == 0) {
            unsigned long long key = ((unsigned long long)enc_f(v) << 32)
                                   | (unsigned long long)(~idx);
            atomicMax(&argOut[(size_t)c * 512 + wf * 64 + NT * 16 + lm], key);
        }
    }
}

// Head + scatter fused: one block per case, 512 threads.
// latent0 = silu(decoded max pre-act) -> split-k layer 1 -> layer 2 in regs ->
// scatter rows with x[b]==c directly (latent never hits global; k_scatter gone).
__global__ __launch_bounds__(512)
void k_head(const unsigned long long* __restrict__ argBuf2,
            const float* __restrict__ W20, const float* __restrict__ b20,
            const float* __restrict__ W21, const float* __restrict__ b21,
            const int* __restrict__ x, float* __restrict__ out)
{
    const int c = blockIdx.x, tid = threadIdx.x;
    __shared__ float l0[512];
    __shared__ float part[2][256];
    __shared__ float hh[256];
    __shared__ int   s_list[OUT_B];
    __shared__ int   s_n;

    l0[tid] = silu_f(dec_f((unsigned)(argBuf2[(size_t)c * 512 + tid] >> 32)));
    if (tid == 0) s_n = 0;
    __syncthreads();

    // layer 1, split-k over 2 halves: hh = silu(l0 @ W20 + b20)
    {
        const int h = tid & 255, half = tid >> 8;
        const float* lv   = l0 + half * 256;
        const float* wcol = W20 + (size_t)(half * 256) * 256 + h;
        float acc = 0.f;
        #pragma unroll 4
        for (int k = 0; k < 256; ++k)
            acc = fmaf(lv[k], wcol[(size_t)k * 256], acc);
        part[half][h] = acc;
    }
    // overlap the x-scan with layer-1 math: each thread classifies 8 rows
    #pragma unroll
    for (int r = 0; r < 8; ++r) {
        int b = r * 512 + tid;
        if (x[b] == c) { int pos = atomicAdd(&s_n, 1); s_list[pos] = b; }
    }
    __syncthreads();
    if (tid < 256)
        hh[tid] = silu_f(part[0][tid] + part[1][tid] + b20[tid]);
    __syncthreads();

    // layer 2: lat[tid] = b21 + hh @ W21 (kept in register)
    float lat = b21[tid];
    #pragma unroll 4
    for (int k = 0; k < 256; ++k)
        lat = fmaf(hh[k], W21[(size_t)k * 512 + tid], lat);

    // scatter: coalesced 2KB row writes
    const int n = s_n;
    for (int i = 0; i < n; ++i)
        out[(size_t)s_list[i] * 512 + tid] = lat;
}

extern "C" void kernel_launch(void* const* d_in, const int* in_sizes, int n_in,
                              void* d_out, int out_size, void* d_ws, size_t ws_size,
                              hipStream_t stream)
{
    const float* pts = (const float*)d_in[0];
    const float* W10 = (const float*)d_in[1];
    const float* b10 = (const float*)d_in[2];
    const float* W11 = (const float*)d_in[3];
    const float* b11 = (const float*)d_in[4];
    const float* W12 = (const float*)d_in[5];
    const float* b12 = (const float*)d_in[6];
    const float* W20 = (const float*)d_in[7];
    const float* b20 = (const float*)d_in[8];
    const float* W21 = (const float*)d_in[9];
    const float* b21 = (const float*)d_in[10];
    const int*   x   = (const int*)d_in[11];
    float* out = (float*)d_out;

    // Workspace layout (re-poisoned every call -> rebuild every call):
    char* ws = (char*)d_ws;
    unsigned long long* argBuf  = (unsigned long long*)ws;              //  64 KB
    unsigned long long* argBuf2 = (unsigned long long*)(ws + 65536);    //  64 KB
    ush* BbWs                   = (ush*)(ws + 131072);                  //  16 KB
    ush* BcWs                   = (ush*)(ws + 147456);                  // 128 KB (total 276 KB)

    // prep: swizzle weights to MFMA B-frag order + zero both argmax buffers
    k_prep<<<dim3(256), dim3(256), 0, stream>>>(W11, W12, BbWs, BcWs, argBuf);

    // Phase 1: big MLP + argmax over 65536 points/case
    k_mlp1_argmax<false><<<dim3(128, NCASES), dim3(512), 0, stream>>>(
        pts, NPTS_BIG, 8, nullptr, W10, b10, b11, b12, BbWs, BcWs, argBuf);

    // Phase 2+3 fused: MLP over 512 critical points/case (gather via argBuf) + max
    k_mlp1_argmax<true><<<dim3(8, NCASES), dim3(512), 0, stream>>>(
        pts, NPTS_BIG, 1, argBuf, W10, b10, b11, b12, BbWs, BcWs, argBuf2);

    // Phase 4+5 fused: head MLP per case + direct scatter to output rows
    k_head<<<dim3(NCASES), dim3(512), 0, stream>>>(
        argBuf2, W20, b20, W21, b21, x, out);
}